// Round 5
// baseline (734.368 us; speedup 1.0000x reference)
//
#include <hip/hip_runtime.h>
#include <stdint.h>

typedef short short8 __attribute__((ext_vector_type(8)));
typedef float floatx4 __attribute__((ext_vector_type(4)));

#define M_TOK 8192
#define K_IN  4096
#define N_OUT 4096

// ---------- bf16 helpers (manual, RNE) ----------
static __device__ __forceinline__ float bf2f(ushort u) {
    union { uint32_t u; float f; } v;
    v.u = ((uint32_t)u) << 16;
    return v.f;
}
static __device__ __forceinline__ ushort f2bf(float f) {
    union { float f; uint32_t u; } v;
    v.f = f;
    uint32_t u = v.u;
    uint32_t r = (u + 0x7FFFu + ((u >> 16) & 1u)) >> 16;
    return (ushort)r;
}

// ---------- mask element-width detection via the 2:4 invariant ----------
// Exactly 2 of each 4 consecutive in_f elements are true per out column.
// Try widths {1,2,4} bytes, truth = "element != 0" (covers 0x01, 0xFF,
// fp16/bf16/f32 1.0, int 1). True width -> 0 violations; wrong widths fail
// most sampled groups. Rows < 1024 keep all probes in-bounds even for a
// 1-byte/elem buffer.
__global__ void detect_mask_kernel(const unsigned char* __restrict__ mb,
                                   int* __restrict__ flags) {
    const ushort* mh = (const ushort*)mb;
    const unsigned int* mw = (const unsigned int*)mb;
    __shared__ int v[3];
    if (threadIdx.x < 3) v[threadIdx.x] = 0;
    __syncthreads();
    int l0 = 0, l1 = 0, l2 = 0;
    for (int s = threadIdx.x; s < 16384; s += 256) {
        int grp = s & 255;
        int o   = (s * 97) & 4095;
        int c1 = 0, c2 = 0, c4 = 0;
        #pragma unroll
        for (int r = 0; r < 4; ++r) {
            size_t idx = (size_t)(4 * grp + r) * N_OUT + o;
            c1 += (mb[idx] != 0);
            c2 += (mh[idx] != 0);
            c4 += (mw[idx] != 0);
        }
        l0 += (c1 != 2); l1 += (c2 != 2); l2 += (c4 != 2);
    }
    atomicAdd(&v[0], l0); atomicAdd(&v[1], l1); atomicAdd(&v[2], l2);
    __syncthreads();
    if (threadIdx.x == 0) {
        int size = 4, best = v[2];
        if (v[1] < best) { size = 2; best = v[1]; }
        if (v[0] < best) { size = 1; }
        flags[0] = size;
    }
}

// ---------- x (f32) -> bf16 workspace ----------
__global__ __launch_bounds__(256) void convert_x_kernel(
    const float* __restrict__ xf, ushort* __restrict__ Xb) {
    const int total = M_TOK * K_IN;
    const int stride = gridDim.x * 256 * 8;
    for (int i = (blockIdx.x * 256 + threadIdx.x) * 8; i < total; i += stride) {
        floatx4 f0 = *(const floatx4*)&xf[i];
        floatx4 f1 = *(const floatx4*)&xf[i + 4];
        short8 v;
        #pragma unroll
        for (int j = 0; j < 4; ++j) v[j]     = (short)f2bf(f0[j]);
        #pragma unroll
        for (int j = 0; j < 4; ++j) v[4 + j] = (short)f2bf(f1[j]);
        *(short8*)&Xb[i] = v;
    }
}

// ---------- dequant + transpose:  Bt[o][i] = bf16( mask ? (q-8)*scale[o] : 0 ) ----------
__global__ __launch_bounds__(256) void dequant_kernel(
    const int* __restrict__ q, const void* __restrict__ maskp,
    const float* __restrict__ scales, ushort* __restrict__ Bt,
    const int* __restrict__ flagp) {
    const int msize = flagp[0];
    const int i0 = blockIdx.x * 64;      // in_f
    const int o0 = blockIdx.y * 64;      // out_f
    const int tid = threadIdx.x;
    const unsigned char* mb = (const unsigned char*)maskp;
    const ushort* mh = (const ushort*)maskp;
    const unsigned int* mi = (const unsigned int*)maskp;
    __shared__ ushort T[64][72];

    for (int p = 0; p < 16; ++p) {
        int idx = p * 256 + tid;
        int r = idx >> 6, c = idx & 63;
        size_t gi = (size_t)(i0 + r) * N_OUT + (o0 + c);
        bool m;
        if (msize == 1)      m = (mb[gi] != 0);
        else if (msize == 2) m = (mh[gi] != 0);
        else                 m = (mi[gi] != 0);
        float s = scales[o0 + c];
        float w = m ? (float)(q[gi] - 8) * s : 0.0f;
        T[r][c] = f2bf(w);
    }
    __syncthreads();
    for (int p = 0; p < 2; ++p) {
        int ol = p * 32 + (tid >> 3);
        int i8 = (tid & 7) * 8;
        short8 v;
        #pragma unroll
        for (int j = 0; j < 8; ++j) v[j] = (short)T[i8 + j][ol];
        *(short8*)&Bt[(size_t)(o0 + ol) * K_IN + i0 + i8] = v;
    }
}

// ---------- bf16 GEMM:  Y(f32) = X * Bt^T  (m97 structure, global_load_lds) ----------
#define GL2L16(gp, lbase)                                                      \
    __builtin_amdgcn_global_load_lds(                                          \
        (const __attribute__((address_space(1))) void*)(gp),                   \
        (__attribute__((address_space(3))) void*)(lbase), 16, 0, 0)

__global__ __launch_bounds__(256) void gemm_kernel(
    const ushort* __restrict__ X,   // [M_TOK][K_IN] bf16 bits (workspace)
    const ushort* __restrict__ Bt,  // [N_OUT][K_IN] bf16 bits (workspace)
    float* __restrict__ Y) {        // [M_TOK][N_OUT] float32
    __shared__ ushort As[128][32];
    __shared__ ushort Bs[128][32];

    const int tid  = threadIdx.x;
    const int w    = tid >> 6;
    const int lane = tid & 63;
    const int row0 = blockIdx.x * 128, col0 = blockIdx.y * 128;
    const int wm = w >> 1, wn = w & 1;

    floatx4 acc[4][4] = {};

    const int sr = tid >> 2;
    const int sc = (tid & 3) * 8;
    const ushort* xa = X  + (size_t)(row0 + sr) * K_IN + sc;
    const ushort* xb = Bt + (size_t)(col0 + sr) * K_IN + sc;
    char* aB0 = (char*)As + (w * 16) * 64;
    char* aB1 = (char*)As + (64 + w * 16) * 64;
    char* bB0 = (char*)Bs + (w * 16) * 64;
    char* bB1 = (char*)Bs + (64 + w * 16) * 64;

    const int fr = lane & 15;
    const int fk = (lane >> 4) * 8;

    for (int kt = 0; kt < K_IN / 32; ++kt) {
        const ushort* ga = xa + kt * 32;
        const ushort* gb = xb + kt * 32;
        GL2L16(ga,                      aB0);
        GL2L16(ga + (size_t)64 * K_IN,  aB1);
        GL2L16(gb,                      bB0);
        GL2L16(gb + (size_t)64 * K_IN,  bB1);
        __syncthreads();

        short8 a[4], b[4];
        #pragma unroll
        for (int m = 0; m < 4; ++m)
            a[m] = *(const short8*)&As[wm * 64 + m * 16 + fr][fk];
        #pragma unroll
        for (int n = 0; n < 4; ++n)
            b[n] = *(const short8*)&Bs[wn * 64 + n * 16 + fr][fk];

        #pragma unroll
        for (int m = 0; m < 4; ++m)
            #pragma unroll
            for (int n = 0; n < 4; ++n)
                acc[m][n] = __builtin_amdgcn_mfma_f32_16x16x32_bf16(
                                a[m], b[n], acc[m][n], 0, 0, 0);
        __syncthreads();
    }

    // C/D layout: col=lane&15, row=(lane>>4)*4+reg (m89-verified). f32 stores.
    const int fq = lane >> 4;
    #pragma unroll
    for (int m = 0; m < 4; ++m)
        #pragma unroll
        for (int n = 0; n < 4; ++n)
            #pragma unroll
            for (int i = 0; i < 4; ++i) {
                int r = row0 + wm * 64 + m * 16 + fq * 4 + i;
                int c = col0 + wn * 64 + n * 16 + fr;
                Y[(size_t)r * N_OUT + c] = acc[m][n][i];
            }
}

// ---------- slow correct fallback (only if ws too small) ----------
__global__ __launch_bounds__(256) void fallback_kernel(
    const float* __restrict__ xf, const int* __restrict__ q,
    const void* __restrict__ maskp, const float* __restrict__ scales,
    float* __restrict__ Y, const int* __restrict__ flagp) {
    const int msize = flagp[0];
    const int o = blockIdx.x * 256 + threadIdx.x;
    const int t = blockIdx.y;
    const unsigned char* mb = (const unsigned char*)maskp;
    const ushort* mh = (const ushort*)maskp;
    const unsigned int* mi = (const unsigned int*)maskp;
    float s = scales[o];
    float acc = 0.f;
    for (int i = 0; i < K_IN; ++i) {
        float x = bf2f(f2bf(xf[(size_t)t * K_IN + i]));
        size_t gi = (size_t)i * N_OUT + o;
        bool m;
        if (msize == 1)      m = (mb[gi] != 0);
        else if (msize == 2) m = (mh[gi] != 0);
        else                 m = (mi[gi] != 0);
        if (m) acc += x * bf2f(f2bf((float)(q[gi] - 8) * s));
    }
    Y[(size_t)t * N_OUT + o] = acc;
}

extern "C" void kernel_launch(void* const* d_in, const int* in_sizes, int n_in,
                              void* d_out, int out_size, void* d_ws, size_t ws_size,
                              hipStream_t stream) {
    const float* x      = (const float*)d_in[0];
    const int*   q      = (const int*)d_in[1];
    const void*  mask   = d_in[2];
    const float* scales = (const float*)d_in[3];
    float* y = (float*)d_out;

    const size_t BT_OFF = 64;
    const size_t XB_OFF = BT_OFF + (size_t)N_OUT * K_IN * 2;   // 64 + 32MB
    const size_t need   = XB_OFF + (size_t)M_TOK * K_IN * 2;   // + 64MB

    int* flags = (int*)d_ws;
    detect_mask_kernel<<<1, 256, 0, stream>>>(
        (const unsigned char*)mask, flags);

    if (ws_size >= need) {
        ushort* Bt = (ushort*)((char*)d_ws + BT_OFF);
        ushort* Xb = (ushort*)((char*)d_ws + XB_OFF);
        convert_x_kernel<<<4096, 256, 0, stream>>>(x, Xb);
        dequant_kernel<<<dim3(K_IN / 64, N_OUT / 64), 256, 0, stream>>>(
            q, mask, scales, Bt, flags);
        gemm_kernel<<<dim3(M_TOK / 128, N_OUT / 128), 256, 0, stream>>>(Xb, Bt, y);
    } else {
        fallback_kernel<<<dim3(N_OUT / 256, M_TOK), 256, 0, stream>>>(
            x, q, mask, scales, y, flags);
    }
}

// Round 6
// 479.452 us; speedup vs baseline: 1.5317x; 1.5317x over previous
//
#include <hip/hip_runtime.h>
#include <stdint.h>

typedef short short8 __attribute__((ext_vector_type(8)));
typedef float floatx4 __attribute__((ext_vector_type(4)));

#define M_TOK 8192
#define K_IN  4096
#define N_OUT 4096

// ---------- bf16 helpers (manual, RNE) ----------
static __device__ __forceinline__ float bf2f(ushort u) {
    union { uint32_t u; float f; } v;
    v.u = ((uint32_t)u) << 16;
    return v.f;
}
static __device__ __forceinline__ ushort f2bf(float f) {
    union { float f; uint32_t u; } v;
    v.f = f;
    uint32_t u = v.u;
    uint32_t r = (u + 0x7FFFu + ((u >> 16) & 1u)) >> 16;
    return (ushort)r;
}

// ---------- mask element-width detection via the 2:4 invariant ----------
// flags[0]=result width (1/2/4 bytes); flags[1..3]=violation counters.
// Parallelized: 64 blocks (the old 1-block version serialized ~200KB of
// scattered HBM loads through a single CU => ~230us).
__global__ void detect_zero_kernel(int* __restrict__ flags) {
    if (threadIdx.x < 3) flags[1 + threadIdx.x] = 0;
}

__global__ __launch_bounds__(256) void detect_count_kernel(
    const unsigned char* __restrict__ mb, int* __restrict__ flags) {
    const ushort* mh = (const ushort*)mb;
    const unsigned int* mw = (const unsigned int*)mb;
    __shared__ int sh[3];
    if (threadIdx.x < 3) sh[threadIdx.x] = 0;
    __syncthreads();
    int s = blockIdx.x * 256 + threadIdx.x;      // 16384 samples
    int grp = s & 255;                           // rows < 1024: in-bounds at all widths
    int o   = (s * 97) & 4095;
    int c1 = 0, c2 = 0, c4 = 0;
    #pragma unroll
    for (int r = 0; r < 4; ++r) {
        size_t idx = (size_t)(4 * grp + r) * N_OUT + o;
        c1 += (mb[idx] != 0);
        c2 += (mh[idx] != 0);
        c4 += (mw[idx] != 0);
    }
    if (c1 != 2) atomicAdd(&sh[0], 1);
    if (c2 != 2) atomicAdd(&sh[1], 1);
    if (c4 != 2) atomicAdd(&sh[2], 1);
    __syncthreads();
    if (threadIdx.x == 0) {
        atomicAdd(&flags[1], sh[0]);
        atomicAdd(&flags[2], sh[1]);
        atomicAdd(&flags[3], sh[2]);
    }
}

__global__ void detect_final_kernel(int* __restrict__ flags) {
    if (threadIdx.x == 0) {
        int size = 4, best = flags[3];
        if (flags[2] < best) { size = 2; best = flags[2]; }
        if (flags[1] < best) { size = 1; }
        flags[0] = size;
    }
}

// ---------- x (f32) -> bf16 workspace ----------
__global__ __launch_bounds__(256) void convert_x_kernel(
    const float* __restrict__ xf, ushort* __restrict__ Xb) {
    const int total = M_TOK * K_IN;
    const int stride = gridDim.x * 256 * 8;
    for (int i = (blockIdx.x * 256 + threadIdx.x) * 8; i < total; i += stride) {
        floatx4 f0 = *(const floatx4*)&xf[i];
        floatx4 f1 = *(const floatx4*)&xf[i + 4];
        short8 v;
        #pragma unroll
        for (int j = 0; j < 4; ++j) v[j]     = (short)f2bf(f0[j]);
        #pragma unroll
        for (int j = 0; j < 4; ++j) v[4 + j] = (short)f2bf(f1[j]);
        *(short8*)&Xb[i] = v;
    }
}

// ---------- dequant + transpose:  Bt[o][i] = bf16( mask ? (q-8)*scale[o] : 0 ) ----------
__global__ __launch_bounds__(256) void dequant_kernel(
    const int* __restrict__ q, const void* __restrict__ maskp,
    const float* __restrict__ scales, ushort* __restrict__ Bt,
    const int* __restrict__ flagp) {
    const int msize = flagp[0];
    const int i0 = blockIdx.x * 64;      // in_f
    const int o0 = blockIdx.y * 64;      // out_f
    const int tid = threadIdx.x;
    const unsigned char* mb = (const unsigned char*)maskp;
    const ushort* mh = (const ushort*)maskp;
    const unsigned int* mi = (const unsigned int*)maskp;
    __shared__ ushort T[64][72];

    for (int p = 0; p < 16; ++p) {
        int idx = p * 256 + tid;
        int r = idx >> 6, c = idx & 63;
        size_t gi = (size_t)(i0 + r) * N_OUT + (o0 + c);
        bool m;
        if (msize == 1)      m = (mb[gi] != 0);
        else if (msize == 2) m = (mh[gi] != 0);
        else                 m = (mi[gi] != 0);
        float s = scales[o0 + c];
        float w = m ? (float)(q[gi] - 8) * s : 0.0f;
        T[r][c] = f2bf(w);
    }
    __syncthreads();
    for (int p = 0; p < 2; ++p) {
        int ol = p * 32 + (tid >> 3);
        int i8 = (tid & 7) * 8;
        short8 v;
        #pragma unroll
        for (int j = 0; j < 8; ++j) v[j] = (short)T[i8 + j][ol];
        *(short8*)&Bt[(size_t)(o0 + ol) * K_IN + i0 + i8] = v;
    }
}

// ---------- bf16 GEMM:  Y(f32) = X * Bt^T  (m97 structure + chunk swizzle) ----------
// LDS tile [128 rows][32 k-elems] = 64B/row = 4 chunks of 16B. Bank math:
// unswizzled fragment reads put each 32-lane half on 4 of 8 bank-quads (2x
// conflict). Swizzle (rule 21, both-sides): LDS stays linear for
// global_load_lds; the GLOBAL source chunk is permuted per lane
// (chunk ^= (row>>1)&3), and fragment reads apply the same involution.
#define GL2L16(gp, lbase)                                                      \
    __builtin_amdgcn_global_load_lds(                                          \
        (const __attribute__((address_space(1))) void*)(gp),                   \
        (__attribute__((address_space(3))) void*)(lbase), 16, 0, 0)

__global__ __launch_bounds__(256) void gemm_kernel(
    const ushort* __restrict__ X,   // [M_TOK][K_IN] bf16 bits (workspace)
    const ushort* __restrict__ Bt,  // [N_OUT][K_IN] bf16 bits (workspace)
    float* __restrict__ Y) {        // [M_TOK][N_OUT] float32
    __shared__ ushort As[128][32];
    __shared__ ushort Bs[128][32];

    const int tid  = threadIdx.x;
    const int w    = tid >> 6;
    const int lane = tid & 63;
    const int row0 = blockIdx.x * 128, col0 = blockIdx.y * 128;
    const int wm = w >> 1, wn = w & 1;

    floatx4 acc[4][4] = {};

    // staging: thread covers LDS slot (row=sr, chunk=tid&3); source column is
    // the swizzled chunk. (row+64 has the same (row>>1)&3 -> same swizzle.)
    const int sr = tid >> 2;
    const int sc = (((tid & 3) ^ ((sr >> 1) & 3)) * 8);
    const ushort* xa = X  + (size_t)(row0 + sr) * K_IN + sc;
    const ushort* xb = Bt + (size_t)(col0 + sr) * K_IN + sc;
    char* aB0 = (char*)As + (w * 16) * 64;
    char* aB1 = (char*)As + (64 + w * 16) * 64;
    char* bB0 = (char*)Bs + (w * 16) * 64;
    char* bB1 = (char*)Bs + (64 + w * 16) * 64;

    const int fr = lane & 15;
    // swizzled k-chunk for fragment reads; (row>>1)&3 == (fr>>1)&3 for all
    // row = wm*64 + m*16 + fr (wm*64, m*16 are multiples of 8).
    const int fk = (((lane >> 4) ^ ((fr >> 1) & 3)) * 8);

    for (int kt = 0; kt < K_IN / 32; ++kt) {
        const ushort* ga = xa + kt * 32;
        const ushort* gb = xb + kt * 32;
        GL2L16(ga,                      aB0);
        GL2L16(ga + (size_t)64 * K_IN,  aB1);
        GL2L16(gb,                      bB0);
        GL2L16(gb + (size_t)64 * K_IN,  bB1);
        __syncthreads();

        short8 a[4], b[4];
        #pragma unroll
        for (int m = 0; m < 4; ++m)
            a[m] = *(const short8*)&As[wm * 64 + m * 16 + fr][fk];
        #pragma unroll
        for (int n = 0; n < 4; ++n)
            b[n] = *(const short8*)&Bs[wn * 64 + n * 16 + fr][fk];

        #pragma unroll
        for (int m = 0; m < 4; ++m)
            #pragma unroll
            for (int n = 0; n < 4; ++n)
                acc[m][n] = __builtin_amdgcn_mfma_f32_16x16x32_bf16(
                                a[m], b[n], acc[m][n], 0, 0, 0);
        __syncthreads();
    }

    // C/D layout: col=lane&15, row=(lane>>4)*4+reg (m89-verified). f32 stores.
    const int fq = lane >> 4;
    #pragma unroll
    for (int m = 0; m < 4; ++m)
        #pragma unroll
        for (int n = 0; n < 4; ++n)
            #pragma unroll
            for (int i = 0; i < 4; ++i) {
                int r = row0 + wm * 64 + m * 16 + fq * 4 + i;
                int c = col0 + wn * 64 + n * 16 + fr;
                Y[(size_t)r * N_OUT + c] = acc[m][n][i];
            }
}

// ---------- slow correct fallback (only if ws too small) ----------
__global__ __launch_bounds__(256) void fallback_kernel(
    const float* __restrict__ xf, const int* __restrict__ q,
    const void* __restrict__ maskp, const float* __restrict__ scales,
    float* __restrict__ Y, const int* __restrict__ flagp) {
    const int msize = flagp[0];
    const int o = blockIdx.x * 256 + threadIdx.x;
    const int t = blockIdx.y;
    const unsigned char* mb = (const unsigned char*)maskp;
    const ushort* mh = (const ushort*)maskp;
    const unsigned int* mi = (const unsigned int*)maskp;
    float s = scales[o];
    float acc = 0.f;
    for (int i = 0; i < K_IN; ++i) {
        float x = bf2f(f2bf(xf[(size_t)t * K_IN + i]));
        size_t gi = (size_t)i * N_OUT + o;
        bool m;
        if (msize == 1)      m = (mb[gi] != 0);
        else if (msize == 2) m = (mh[gi] != 0);
        else                 m = (mi[gi] != 0);
        if (m) acc += x * bf2f(f2bf((float)(q[gi] - 8) * s));
    }
    Y[(size_t)t * N_OUT + o] = acc;
}

extern "C" void kernel_launch(void* const* d_in, const int* in_sizes, int n_in,
                              void* d_out, int out_size, void* d_ws, size_t ws_size,
                              hipStream_t stream) {
    const float* x      = (const float*)d_in[0];
    const int*   q      = (const int*)d_in[1];
    const void*  mask   = d_in[2];
    const float* scales = (const float*)d_in[3];
    float* y = (float*)d_out;

    const size_t BT_OFF = 64;
    const size_t XB_OFF = BT_OFF + (size_t)N_OUT * K_IN * 2;   // 64 + 32MB
    const size_t need   = XB_OFF + (size_t)M_TOK * K_IN * 2;   // + 64MB

    int* flags = (int*)d_ws;
    detect_zero_kernel<<<1, 64, 0, stream>>>(flags);
    detect_count_kernel<<<64, 256, 0, stream>>>(
        (const unsigned char*)mask, flags);
    detect_final_kernel<<<1, 64, 0, stream>>>(flags);

    if (ws_size >= need) {
        ushort* Bt = (ushort*)((char*)d_ws + BT_OFF);
        ushort* Xb = (ushort*)((char*)d_ws + XB_OFF);
        convert_x_kernel<<<4096, 256, 0, stream>>>(x, Xb);
        dequant_kernel<<<dim3(K_IN / 64, N_OUT / 64), 256, 0, stream>>>(
            q, mask, scales, Bt, flags);
        gemm_kernel<<<dim3(M_TOK / 128, N_OUT / 128), 256, 0, stream>>>(Xb, Bt, y);
    } else {
        fallback_kernel<<<dim3(N_OUT / 256, M_TOK), 256, 0, stream>>>(
            x, q, mask, scales, y, flags);
    }
}

// Round 7
// 400.830 us; speedup vs baseline: 1.8321x; 1.1961x over previous
//
#include <hip/hip_runtime.h>
#include <stdint.h>

typedef short short8 __attribute__((ext_vector_type(8)));
typedef float floatx4 __attribute__((ext_vector_type(4)));

#define M_TOK 8192
#define K_IN  4096
#define N_OUT 4096
#define NT    (K_IN / 64)

// ---------- bf16 helpers (manual, RNE) ----------
static __device__ __forceinline__ float bf2f(ushort u) {
    union { uint32_t u; float f; } v;
    v.u = ((uint32_t)u) << 16;
    return v.f;
}
static __device__ __forceinline__ ushort f2bf(float f) {
    union { float f; uint32_t u; } v;
    v.f = f;
    uint32_t u = v.u;
    uint32_t r = (u + 0x7FFFu + ((u >> 16) & 1u)) >> 16;
    return (ushort)r;
}

// ---------- mask element-width detection via the 2:4 invariant ----------
__global__ void detect_zero_kernel(int* __restrict__ flags) {
    if (threadIdx.x < 3) flags[1 + threadIdx.x] = 0;
}

__global__ __launch_bounds__(256) void detect_count_kernel(
    const unsigned char* __restrict__ mb, int* __restrict__ flags) {
    const ushort* mh = (const ushort*)mb;
    const unsigned int* mw = (const unsigned int*)mb;
    __shared__ int sh[3];
    if (threadIdx.x < 3) sh[threadIdx.x] = 0;
    __syncthreads();
    int s = blockIdx.x * 256 + threadIdx.x;      // 16384 samples
    int grp = s & 255;                           // rows < 1024: in-bounds at all widths
    int o   = (s * 97) & 4095;
    int c1 = 0, c2 = 0, c4 = 0;
    #pragma unroll
    for (int r = 0; r < 4; ++r) {
        size_t idx = (size_t)(4 * grp + r) * N_OUT + o;
        c1 += (mb[idx] != 0);
        c2 += (mh[idx] != 0);
        c4 += (mw[idx] != 0);
    }
    if (c1 != 2) atomicAdd(&sh[0], 1);
    if (c2 != 2) atomicAdd(&sh[1], 1);
    if (c4 != 2) atomicAdd(&sh[2], 1);
    __syncthreads();
    if (threadIdx.x == 0) {
        atomicAdd(&flags[1], sh[0]);
        atomicAdd(&flags[2], sh[1]);
        atomicAdd(&flags[3], sh[2]);
    }
}

__global__ void detect_final_kernel(int* __restrict__ flags) {
    if (threadIdx.x == 0) {
        int size = 4, best = flags[3];
        if (flags[2] < best) { size = 2; best = flags[2]; }
        if (flags[1] < best) { size = 1; }
        flags[0] = size;
    }
}

// ---------- x (f32) -> bf16 workspace ----------
__global__ __launch_bounds__(256) void convert_x_kernel(
    const float* __restrict__ xf, ushort* __restrict__ Xb) {
    const int total = M_TOK * K_IN;
    const int stride = gridDim.x * 256 * 8;
    for (int i = (blockIdx.x * 256 + threadIdx.x) * 8; i < total; i += stride) {
        floatx4 f0 = *(const floatx4*)&xf[i];
        floatx4 f1 = *(const floatx4*)&xf[i + 4];
        short8 v;
        #pragma unroll
        for (int j = 0; j < 4; ++j) v[j]     = (short)f2bf(f0[j]);
        #pragma unroll
        for (int j = 0; j < 4; ++j) v[4 + j] = (short)f2bf(f1[j]);
        *(short8*)&Xb[i] = v;
    }
}

// ---------- dequant + transpose:  Bt[o][i] = bf16( mask ? (q-8)*scale[o] : 0 ) ----------
__global__ __launch_bounds__(256) void dequant_kernel(
    const int* __restrict__ q, const void* __restrict__ maskp,
    const float* __restrict__ scales, ushort* __restrict__ Bt,
    const int* __restrict__ flagp) {
    const int msize = flagp[0];
    const int i0 = blockIdx.x * 64;      // in_f
    const int o0 = blockIdx.y * 64;      // out_f
    const int tid = threadIdx.x;
    const unsigned char* mb = (const unsigned char*)maskp;
    const ushort* mh = (const ushort*)maskp;
    const unsigned int* mi = (const unsigned int*)maskp;
    __shared__ ushort T[64][72];

    for (int p = 0; p < 16; ++p) {
        int idx = p * 256 + tid;
        int r = idx >> 6, c = idx & 63;
        size_t gi = (size_t)(i0 + r) * N_OUT + (o0 + c);
        bool m;
        if (msize == 1)      m = (mb[gi] != 0);
        else if (msize == 2) m = (mh[gi] != 0);
        else                 m = (mi[gi] != 0);
        float s = scales[o0 + c];
        float w = m ? (float)(q[gi] - 8) * s : 0.0f;
        T[r][c] = f2bf(w);
    }
    __syncthreads();
    for (int p = 0; p < 2; ++p) {
        int ol = p * 32 + (tid >> 3);
        int i8 = (tid & 7) * 8;
        short8 v;
        #pragma unroll
        for (int j = 0; j < 8; ++j) v[j] = (short)T[i8 + j][ol];
        *(short8*)&Bt[(size_t)(o0 + ol) * K_IN + i0 + i8] = v;
    }
}

// ---------- bf16 GEMM: 256x256 tile, BK=64, 8 waves, dbuf LDS, counted vmcnt ----------
// LDS tile [256 rows][64 k] = 128 B/row = 8 chunks of 16 B.
// Swizzle (rule 21, both-sides): LDS[r][c] holds global chunk c ^ (r&7).
//   stage: source chunk = (lane&7) ^ (lane>>3)  (row%8 == lane>>3)
//   read : chunk = (kk*4 + g) ^ (fr&7)
// => every ds_read_b128 hits exactly 8 lanes per 16B bank-quad (the floor).
#define GL2L16(gp, lbase)                                                      \
    __builtin_amdgcn_global_load_lds(                                          \
        (const __attribute__((address_space(1))) void*)(gp),                   \
        (__attribute__((address_space(3))) void*)(lbase), 16, 0, 0)

__global__ __launch_bounds__(512, 2) void gemm_kernel(
    const ushort* __restrict__ X,   // [M_TOK][K_IN] bf16 bits (workspace)
    const ushort* __restrict__ Bt,  // [N_OUT][K_IN] bf16 bits (workspace)
    float* __restrict__ Y) {        // [M_TOK][N_OUT] float32
    __shared__ ushort As[2][256][64];   // 64 KiB
    __shared__ ushort Bs[2][256][64];   // 64 KiB

    const int tid  = threadIdx.x;
    const int w    = tid >> 6;          // 0..7
    const int lane = tid & 63;

    // T1: bijective XCD swizzle (512 % 8 == 0), M fast-varying within an XCD
    const int sw   = ((blockIdx.x & 7) << 6) + (blockIdx.x >> 3);
    const int row0 = (sw & 31) * 256;   // 32 M-tiles
    const int col0 = (sw >> 5) * 256;   // 16 N-tiles
    const int wm = w >> 2, wn = w & 3;  // 2 x 4 wave grid; per-wave C = 128x64

    floatx4 acc[8][4] = {};

    // staging map: wave w covers rows p*64 + w*8 + (lane>>3), chunk lane&7
    const int srow   = (w << 3) + (lane >> 3);
    const int schunk = (lane & 7) ^ (lane >> 3);
    const ushort* gA = X  + (size_t)(row0 + srow) * K_IN + schunk * 8;
    const ushort* gB = Bt + (size_t)(col0 + srow) * K_IN + schunk * 8;

    const int fr = lane & 15, g = lane >> 4;
    const int fx = fr & 7;

    // prologue: tile 0 -> buf0 (oldest 8), tile 1 -> buf1
    #pragma unroll
    for (int p = 0; p < 4; ++p) {
        GL2L16(gA + (size_t)p * 64 * K_IN, (char*)&As[0][p * 64 + w * 8][0] + lane * 16);
        GL2L16(gB + (size_t)p * 64 * K_IN, (char*)&Bs[0][p * 64 + w * 8][0] + lane * 16);
    }
    #pragma unroll
    for (int p = 0; p < 4; ++p) {
        GL2L16(gA + (size_t)p * 64 * K_IN + 64, (char*)&As[1][p * 64 + w * 8][0] + lane * 16);
        GL2L16(gB + (size_t)p * 64 * K_IN + 64, (char*)&Bs[1][p * 64 + w * 8][0] + lane * 16);
    }

    for (int t = 0; t < NT; ++t) {
        const int d = t & 1;
        // tile t resident: own 8 oldest loads landed, then barrier => all waves'
        if (t + 1 < NT) asm volatile("s_waitcnt vmcnt(8)" ::: "memory");
        else            asm volatile("s_waitcnt vmcnt(0)" ::: "memory");
        __builtin_amdgcn_s_barrier();
        __builtin_amdgcn_sched_barrier(0);

        // ---- kk = 0: read 12 frags, 32 MFMA ----
        short8 a0[8], b0[4];
        #pragma unroll
        for (int m = 0; m < 8; ++m)
            a0[m] = *(const short8*)&As[d][wm * 128 + m * 16 + fr][(g ^ fx) * 8];
        #pragma unroll
        for (int n = 0; n < 4; ++n)
            b0[n] = *(const short8*)&Bs[d][wn * 64 + n * 16 + fr][(g ^ fx) * 8];
        __builtin_amdgcn_s_setprio(1);
        #pragma unroll
        for (int m = 0; m < 8; ++m)
            #pragma unroll
            for (int n = 0; n < 4; ++n)
                acc[m][n] = __builtin_amdgcn_mfma_f32_16x16x32_bf16(
                                a0[m], b0[n], acc[m][n], 0, 0, 0);
        __builtin_amdgcn_s_setprio(0);

        // ---- kk = 1: read 12 frags ----
        short8 a1[8], b1[4];
        #pragma unroll
        for (int m = 0; m < 8; ++m)
            a1[m] = *(const short8*)&As[d][wm * 128 + m * 16 + fr][((4 + g) ^ fx) * 8];
        #pragma unroll
        for (int n = 0; n < 4; ++n)
            b1[n] = *(const short8*)&Bs[d][wn * 64 + n * 16 + fr][((4 + g) ^ fx) * 8];

        // all reads of buf d complete in-regs, then free it for restaging
        asm volatile("s_waitcnt lgkmcnt(0)" ::: "memory");
        __builtin_amdgcn_sched_barrier(0);
        __builtin_amdgcn_s_barrier();
        __builtin_amdgcn_sched_barrier(0);

        if (t + 2 < NT) {
            const ushort* ga = gA + (size_t)(t + 2) * 64;
            const ushort* gb = gB + (size_t)(t + 2) * 64;
            #pragma unroll
            for (int p = 0; p < 4; ++p) {
                GL2L16(ga + (size_t)p * 64 * K_IN, (char*)&As[d][p * 64 + w * 8][0] + lane * 16);
                GL2L16(gb + (size_t)p * 64 * K_IN, (char*)&Bs[d][p * 64 + w * 8][0] + lane * 16);
            }
        }

        __builtin_amdgcn_s_setprio(1);
        #pragma unroll
        for (int m = 0; m < 8; ++m)
            #pragma unroll
            for (int n = 0; n < 4; ++n)
                acc[m][n] = __builtin_amdgcn_mfma_f32_16x16x32_bf16(
                                a1[m], b1[n], acc[m][n], 0, 0, 0);
        __builtin_amdgcn_s_setprio(0);
    }

    // epilogue: C/D layout col=lane&15, row=(lane>>4)*4+reg (m89-verified)
    const int fq = lane >> 4;
    #pragma unroll
    for (int m = 0; m < 8; ++m)
        #pragma unroll
        for (int n = 0; n < 4; ++n)
            #pragma unroll
            for (int i = 0; i < 4; ++i) {
                int r = row0 + wm * 128 + m * 16 + fq * 4 + i;
                int c = col0 + wn * 64 + n * 16 + fr;
                Y[(size_t)r * N_OUT + c] = acc[m][n][i];
            }
}

// ---------- slow correct fallback (only if ws too small) ----------
__global__ __launch_bounds__(256) void fallback_kernel(
    const float* __restrict__ xf, const int* __restrict__ q,
    const void* __restrict__ maskp, const float* __restrict__ scales,
    float* __restrict__ Y, const int* __restrict__ flagp) {
    const int msize = flagp[0];
    const int o = blockIdx.x * 256 + threadIdx.x;
    const int t = blockIdx.y;
    const unsigned char* mb = (const unsigned char*)maskp;
    const ushort* mh = (const ushort*)maskp;
    const unsigned int* mi = (const unsigned int*)maskp;
    float s = scales[o];
    float acc = 0.f;
    for (int i = 0; i < K_IN; ++i) {
        float x = bf2f(f2bf(xf[(size_t)t * K_IN + i]));
        size_t gi = (size_t)i * N_OUT + o;
        bool m;
        if (msize == 1)      m = (mb[gi] != 0);
        else if (msize == 2) m = (mh[gi] != 0);
        else                 m = (mi[gi] != 0);
        if (m) acc += x * bf2f(f2bf((float)(q[gi] - 8) * s));
    }
    Y[(size_t)t * N_OUT + o] = acc;
}

extern "C" void kernel_launch(void* const* d_in, const int* in_sizes, int n_in,
                              void* d_out, int out_size, void* d_ws, size_t ws_size,
                              hipStream_t stream) {
    const float* x      = (const float*)d_in[0];
    const int*   q      = (const int*)d_in[1];
    const void*  mask   = d_in[2];
    const float* scales = (const float*)d_in[3];
    float* y = (float*)d_out;

    const size_t BT_OFF = 64;
    const size_t XB_OFF = BT_OFF + (size_t)N_OUT * K_IN * 2;   // 64 + 32MB
    const size_t need   = XB_OFF + (size_t)M_TOK * K_IN * 2;   // + 64MB

    int* flags = (int*)d_ws;
    detect_zero_kernel<<<1, 64, 0, stream>>>(flags);
    detect_count_kernel<<<64, 256, 0, stream>>>(
        (const unsigned char*)mask, flags);
    detect_final_kernel<<<1, 64, 0, stream>>>(flags);

    if (ws_size >= need) {
        ushort* Bt = (ushort*)((char*)d_ws + BT_OFF);
        ushort* Xb = (ushort*)((char*)d_ws + XB_OFF);
        convert_x_kernel<<<4096, 256, 0, stream>>>(x, Xb);
        dequant_kernel<<<dim3(K_IN / 64, N_OUT / 64), 256, 0, stream>>>(
            q, mask, scales, Bt, flags);
        gemm_kernel<<<dim3((M_TOK / 256) * (N_OUT / 256)), 512, 0, stream>>>(
            Xb, Bt, y);
    } else {
        fallback_kernel<<<dim3(N_OUT / 256, M_TOK), 256, 0, stream>>>(
            x, q, mask, scales, y, flags);
    }
}

// Round 8
// 390.641 us; speedup vs baseline: 1.8799x; 1.0261x over previous
//
#include <hip/hip_runtime.h>
#include <stdint.h>

typedef short short8 __attribute__((ext_vector_type(8)));
typedef float floatx4 __attribute__((ext_vector_type(4)));

#define M_TOK 8192
#define K_IN  4096
#define N_OUT 4096
#define NT    (K_IN / 64)

// ---------- bf16 helpers (manual, RNE) ----------
static __device__ __forceinline__ float bf2f(ushort u) {
    union { uint32_t u; float f; } v;
    v.u = ((uint32_t)u) << 16;
    return v.f;
}
static __device__ __forceinline__ ushort f2bf(float f) {
    union { float f; uint32_t u; } v;
    v.f = f;
    uint32_t u = v.u;
    uint32_t r = (u + 0x7FFFu + ((u >> 16) & 1u)) >> 16;
    return (ushort)r;
}

// ---------- mask element-width detection via the 2:4 invariant ----------
__global__ void detect_zero_kernel(int* __restrict__ flags) {
    if (threadIdx.x < 3) flags[1 + threadIdx.x] = 0;
}

__global__ __launch_bounds__(256) void detect_count_kernel(
    const unsigned char* __restrict__ mb, int* __restrict__ flags) {
    const ushort* mh = (const ushort*)mb;
    const unsigned int* mw = (const unsigned int*)mb;
    __shared__ int sh[3];
    if (threadIdx.x < 3) sh[threadIdx.x] = 0;
    __syncthreads();
    int s = blockIdx.x * 256 + threadIdx.x;      // 16384 samples
    int grp = s & 255;                           // rows < 1024: in-bounds at all widths
    int o   = (s * 97) & 4095;
    int c1 = 0, c2 = 0, c4 = 0;
    #pragma unroll
    for (int r = 0; r < 4; ++r) {
        size_t idx = (size_t)(4 * grp + r) * N_OUT + o;
        c1 += (mb[idx] != 0);
        c2 += (mh[idx] != 0);
        c4 += (mw[idx] != 0);
    }
    if (c1 != 2) atomicAdd(&sh[0], 1);
    if (c2 != 2) atomicAdd(&sh[1], 1);
    if (c4 != 2) atomicAdd(&sh[2], 1);
    __syncthreads();
    if (threadIdx.x == 0) {
        atomicAdd(&flags[1], sh[0]);
        atomicAdd(&flags[2], sh[1]);
        atomicAdd(&flags[3], sh[2]);
    }
}

__global__ void detect_final_kernel(int* __restrict__ flags) {
    if (threadIdx.x == 0) {
        int size = 4, best = flags[3];
        if (flags[2] < best) { size = 2; best = flags[2]; }
        if (flags[1] < best) { size = 1; }
        flags[0] = size;
    }
}

// ---------- x (f32) -> bf16 workspace ----------
__global__ __launch_bounds__(256) void convert_x_kernel(
    const float* __restrict__ xf, ushort* __restrict__ Xb) {
    const int total = M_TOK * K_IN;
    const int stride = gridDim.x * 256 * 8;
    for (int i = (blockIdx.x * 256 + threadIdx.x) * 8; i < total; i += stride) {
        floatx4 f0 = *(const floatx4*)&xf[i];
        floatx4 f1 = *(const floatx4*)&xf[i + 4];
        short8 v;
        #pragma unroll
        for (int j = 0; j < 4; ++j) v[j]     = (short)f2bf(f0[j]);
        #pragma unroll
        for (int j = 0; j < 4; ++j) v[4 + j] = (short)f2bf(f1[j]);
        *(short8*)&Xb[i] = v;
    }
}

// ---------- dequant + transpose:  Bt[o][i] = bf16( mask ? (q-8)*scale[o] : 0 ) ----------
__global__ __launch_bounds__(256) void dequant_kernel(
    const int* __restrict__ q, const void* __restrict__ maskp,
    const float* __restrict__ scales, ushort* __restrict__ Bt,
    const int* __restrict__ flagp) {
    const int msize = flagp[0];
    const int i0 = blockIdx.x * 64;      // in_f
    const int o0 = blockIdx.y * 64;      // out_f
    const int tid = threadIdx.x;
    const unsigned char* mb = (const unsigned char*)maskp;
    const ushort* mh = (const ushort*)maskp;
    const unsigned int* mi = (const unsigned int*)maskp;
    __shared__ ushort T[64][72];

    for (int p = 0; p < 16; ++p) {
        int idx = p * 256 + tid;
        int r = idx >> 6, c = idx & 63;
        size_t gi = (size_t)(i0 + r) * N_OUT + (o0 + c);
        bool m;
        if (msize == 1)      m = (mb[gi] != 0);
        else if (msize == 2) m = (mh[gi] != 0);
        else                 m = (mi[gi] != 0);
        float s = scales[o0 + c];
        float w = m ? (float)(q[gi] - 8) * s : 0.0f;
        T[r][c] = f2bf(w);
    }
    __syncthreads();
    for (int p = 0; p < 2; ++p) {
        int ol = p * 32 + (tid >> 3);
        int i8 = (tid & 7) * 8;
        short8 v;
        #pragma unroll
        for (int j = 0; j < 8; ++j) v[j] = (short)T[i8 + j][ol];
        *(short8*)&Bt[(size_t)(o0 + ol) * K_IN + i0 + i8] = v;
    }
}

// ---------- bf16 GEMM: 256x256, BK=64, 8 waves, 8-phase dbuf pipeline ----------
// Phases per iter (2 K-tiles t=2i,2i+1): p1-4 compute tile t (buf0), one
// (mh,kk) quadrant each (16 MFMA); p5-8 compute tile t+1 (buf1).
// Stage slots (half = 128 rows x 64 k, 2 gl2lds/thread), target freed 1+
// barrier earlier: p1:A1(t+1,buf1) p2:B0(t+1) p3:B1(t+1) p4:A0(t+2,buf0)
// p5:A1(t+2) p6:B0(t+2) p7:B1(t+2) p8:A0(t+3,buf1).
// Counted vmcnt at p4/p8 end only (never 0 until the tail guard trims).
// Swizzle (rule 21 both-sides): LDS[r][c] holds global chunk c^(r&7).
#define GL2L16(gp, lbase)                                                      \
    __builtin_amdgcn_global_load_lds(                                          \
        (const __attribute__((address_space(1))) void*)(gp),                   \
        (__attribute__((address_space(3))) void*)(lbase), 16, 0, 0)

__global__ __launch_bounds__(512, 2) void gemm_kernel(
    const ushort* __restrict__ X,   // [M_TOK][K_IN] bf16 bits (workspace)
    const ushort* __restrict__ Bt,  // [N_OUT][K_IN] bf16 bits (workspace)
    float* __restrict__ Y) {        // [M_TOK][N_OUT] float32
    __shared__ ushort As0[256][64], As1[256][64];
    __shared__ ushort Bs0[256][64], Bs1[256][64];

    const int tid  = threadIdx.x;
    const int w    = tid >> 6;          // 0..7
    const int lane = tid & 63;

    // T1: bijective XCD swizzle (512 % 8 == 0), M fast-varying within an XCD
    const int sw   = ((blockIdx.x & 7) << 6) + (blockIdx.x >> 3);
    const int row0 = (sw & 31) * 256;
    const int col0 = (sw >> 5) * 256;
    const int wm = w >> 2, wn = w & 3;  // per-wave C = 128x64

    floatx4 acc[8][4] = {};

    const int srow   = (w << 3) + (lane >> 3);
    const int schunk = (lane & 7) ^ (lane >> 3);
    const ushort* gA = X  + (size_t)(row0 + srow) * K_IN + schunk * 8;
    const ushort* gB = Bt + (size_t)(col0 + srow) * K_IN + schunk * 8;

    const int fr = lane & 15, g = lane >> 4;
    const int fx = fr & 7;

    // stage one 128-row half (h=0/1) of k-tile tt from gbase into buf
    #define STG(gbase, buf, h, tt)                                             \
        do {                                                                   \
            GL2L16(gbase + (size_t)((h) * 128) * K_IN + (size_t)(tt) * 64,     \
                   (char*)&buf[(h) * 128 + w * 8][0] + lane * 16);             \
            GL2L16(gbase + (size_t)((h) * 128 + 64) * K_IN + (size_t)(tt) * 64,\
                   (char*)&buf[(h) * 128 + 64 + w * 8][0] + lane * 16);        \
        } while (0)

    // one phase: reads (4 or 8 ds_read_b128) || stage || bar || lgkm || 16 MFMA
    #define PHASE(As_, Bs_, MH, KKC, bfr, READB, STAGE_STMT, VMCNT_STMT)       \
        do {                                                                   \
            if (READB) {                                                       \
                _Pragma("unroll")                                              \
                for (int n = 0; n < 4; ++n)                                    \
                    bfr[n] = *(const short8*)&Bs_[wn * 64 + n * 16 + fr]       \
                                 [(((KKC) * 4 + g) ^ fx) * 8];                 \
            }                                                                  \
            short8 afr[4];                                                     \
            _Pragma("unroll")                                                  \
            for (int m = 0; m < 4; ++m)                                        \
                afr[m] = *(const short8*)&As_[wm * 128 + ((MH) * 4 + m) * 16 + fr] \
                             [(((KKC) * 4 + g) ^ fx) * 8];                     \
            STAGE_STMT;                                                        \
            __builtin_amdgcn_s_barrier();                                      \
            asm volatile("s_waitcnt lgkmcnt(0)" ::: "memory");                 \
            __builtin_amdgcn_sched_barrier(0);                                 \
            __builtin_amdgcn_s_setprio(1);                                     \
            _Pragma("unroll")                                                  \
            for (int m = 0; m < 4; ++m)                                        \
                _Pragma("unroll")                                              \
                for (int n = 0; n < 4; ++n)                                    \
                    acc[(MH) * 4 + m][n] = __builtin_amdgcn_mfma_f32_16x16x32_bf16( \
                        afr[m], bfr[n], acc[(MH) * 4 + m][n], 0, 0, 0);        \
            __builtin_amdgcn_s_setprio(0);                                     \
            VMCNT_STMT;                                                        \
            __builtin_amdgcn_s_barrier();                                      \
        } while (0)

    // prologue: tile0 (all 4 halves -> buf0) + tile1 A-half0 -> buf1
    STG(gA, As0, 0, 0); STG(gA, As0, 1, 0);
    STG(gB, Bs0, 0, 0); STG(gB, Bs0, 1, 0);
    STG(gA, As1, 0, 1);
    asm volatile("s_waitcnt vmcnt(2)" ::: "memory");
    __builtin_amdgcn_s_barrier();

    short8 bfr0[4], bfr1[4];

    for (int i = 0; i < NT / 2; ++i) {
        const int t1 = 2 * i + 1, t2 = 2 * i + 2, t3 = 2 * i + 3;
        const bool s2 = (t2 < NT), s3 = (t3 < NT);

        // ---- tile 2i from buf0 ----
        PHASE(As0, Bs0, 0, 0, bfr0, 1, STG(gA, As1, 1, t1), );
        PHASE(As0, Bs0, 1, 0, bfr0, 0, STG(gB, Bs1, 0, t1), );
        PHASE(As0, Bs0, 0, 1, bfr1, 1, STG(gB, Bs1, 1, t1), );
        PHASE(As0, Bs0, 1, 1, bfr1, 0,
              if (s2) STG(gA, As0, 0, t2),
              if (s2) { asm volatile("s_waitcnt vmcnt(2)" ::: "memory"); }
              else    { asm volatile("s_waitcnt vmcnt(0)" ::: "memory"); });

        // ---- tile 2i+1 from buf1 ----
        PHASE(As1, Bs1, 0, 0, bfr0, 1, if (s2) STG(gA, As0, 1, t2), );
        PHASE(As1, Bs1, 1, 0, bfr0, 0, if (s2) STG(gB, Bs0, 0, t2), );
        PHASE(As1, Bs1, 0, 1, bfr1, 1, if (s2) STG(gB, Bs0, 1, t2), );
        PHASE(As1, Bs1, 1, 1, bfr1, 0,
              if (s3) STG(gA, As1, 0, t3),
              if (s3) { asm volatile("s_waitcnt vmcnt(2)" ::: "memory"); }
              else    { asm volatile("s_waitcnt vmcnt(0)" ::: "memory"); });
    }

    // epilogue: C/D layout col=lane&15, row=(lane>>4)*4+reg (m89-verified)
    const int fq = lane >> 4;
    #pragma unroll
    for (int m = 0; m < 8; ++m)
        #pragma unroll
        for (int n = 0; n < 4; ++n)
            #pragma unroll
            for (int i = 0; i < 4; ++i) {
                int r = row0 + wm * 128 + m * 16 + fq * 4 + i;
                int c = col0 + wn * 64 + n * 16 + fr;
                Y[(size_t)r * N_OUT + c] = acc[m][n][i];
            }
    #undef PHASE
    #undef STG
}

// ---------- slow correct fallback (only if ws too small) ----------
__global__ __launch_bounds__(256) void fallback_kernel(
    const float* __restrict__ xf, const int* __restrict__ q,
    const void* __restrict__ maskp, const float* __restrict__ scales,
    float* __restrict__ Y, const int* __restrict__ flagp) {
    const int msize = flagp[0];
    const int o = blockIdx.x * 256 + threadIdx.x;
    const int t = blockIdx.y;
    const unsigned char* mb = (const unsigned char*)maskp;
    const ushort* mh = (const ushort*)maskp;
    const unsigned int* mi = (const unsigned int*)maskp;
    float s = scales[o];
    float acc = 0.f;
    for (int i = 0; i < K_IN; ++i) {
        float x = bf2f(f2bf(xf[(size_t)t * K_IN + i]));
        size_t gi = (size_t)i * N_OUT + o;
        bool m;
        if (msize == 1)      m = (mb[gi] != 0);
        else if (msize == 2) m = (mh[gi] != 0);
        else                 m = (mi[gi] != 0);
        if (m) acc += x * bf2f(f2bf((float)(q[gi] - 8) * s));
    }
    Y[(size_t)t * N_OUT + o] = acc;
}

extern "C" void kernel_launch(void* const* d_in, const int* in_sizes, int n_in,
                              void* d_out, int out_size, void* d_ws, size_t ws_size,
                              hipStream_t stream) {
    const float* x      = (const float*)d_in[0];
    const int*   q      = (const int*)d_in[1];
    const void*  mask   = d_in[2];
    const float* scales = (const float*)d_in[3];
    float* y = (float*)d_out;

    const size_t BT_OFF = 64;
    const size_t XB_OFF = BT_OFF + (size_t)N_OUT * K_IN * 2;   // 64 + 32MB
    const size_t need   = XB_OFF + (size_t)M_TOK * K_IN * 2;   // + 64MB

    int* flags = (int*)d_ws;
    detect_zero_kernel<<<1, 64, 0, stream>>>(flags);
    detect_count_kernel<<<64, 256, 0, stream>>>(
        (const unsigned char*)mask, flags);
    detect_final_kernel<<<1, 64, 0, stream>>>(flags);

    if (ws_size >= need) {
        ushort* Bt = (ushort*)((char*)d_ws + BT_OFF);
        ushort* Xb = (ushort*)((char*)d_ws + XB_OFF);
        convert_x_kernel<<<4096, 256, 0, stream>>>(x, Xb);
        dequant_kernel<<<dim3(K_IN / 64, N_OUT / 64), 256, 0, stream>>>(
            q, mask, scales, Bt, flags);
        gemm_kernel<<<dim3((M_TOK / 256) * (N_OUT / 256)), 512, 0, stream>>>(
            Xb, Bt, y);
    } else {
        fallback_kernel<<<dim3(N_OUT / 256, M_TOK), 256, 0, stream>>>(
            x, q, mask, scales, y, flags);
    }
}